// Round 6
// baseline (114.349 us; speedup 1.0000x reference)
//
#include <hip/hip_runtime.h>

#define BTOT 8192
#define TT 512
#define LOG2E 1.44269504089f

__device__ __forceinline__ float rcp_f(float x)  { return __builtin_amdgcn_rcpf(x); }
__device__ __forceinline__ float exp2_f(float x) { return __builtin_amdgcn_exp2f(x); }
__device__ __forceinline__ float bperm(int addr4, float v) {
    return __int_as_float(__builtin_amdgcn_ds_bpermute(addr4, __float_as_int(v)));
}
template<int CTRL>
__device__ __forceinline__ float qb(float v) {   // quad_perm broadcast
    return __int_as_float(__builtin_amdgcn_mov_dpp(__float_as_int(v), CTRL, 0xf, 0xf, true));
}

__global__ __launch_bounds__(64) void lstm_kernel(
    const float* __restrict__ x,
    const float* __restrict__ W_ih,
    const float* __restrict__ W_hh,
    const float* __restrict__ b_ih,
    const float* __restrict__ b_hh,
    const float* __restrict__ fc1_w,
    const float* __restrict__ fc1_b,
    const float* __restrict__ fc2_w,
    const float* __restrict__ fc2_b,
    float* __restrict__ out)
{
    const int lane   = threadIdx.x;                 // one wave per block
    const int ll     = (lane < 60) ? lane : 59;     // idle lanes alias lane 59
    const int bw     = ll / 20;                     // batch within wave: 0..2
    const int within = ll % 20;                     // row slot within batch group
    const int j      = within >> 2;                 // hidden unit (quad index, 0..4)
    const int g      = within & 3;                  // gate (0=i,1=f,2=g,3=o)
    const int base   = bw * 20;                     // group base lane (0/20/40, 4-aligned)
    const int b_raw  = blockIdx.x * 3 + bw;
    const bool write_ok = (lane < 60) && (within == 0) && (b_raw < BTOT);
    const int b = (b_raw < BTOT) ? b_raw : (BTOT - 1);

    // fold activation scaling (incl log2e for raw exp2) into weights:
    //  i,f,o: acc = -z*log2e -> sigmoid(z) =     rcp(1+exp2(acc))
    //  g    : acc = 2z*log2e -> tanh(z)    = 1 - 2*rcp(1+exp2(acc))
    const float sc   = (g == 2) ? (2.0f * LOG2E) : (-LOG2E);
    const float selA = (g == 2) ? -2.0f :  1.0f;
    const float selB = (g == 2) ?  1.0f :  0.0f;

    // exactly ONE row per lane (PyTorch gate-major: row = g*5 + j)
    const int row = g * 5 + j;
    float wih[5], whh[5];
    #pragma unroll
    for (int i = 0; i < 5; ++i) {
        wih[i] = sc * W_ih[row * 5 + i];
        whh[i] = sc * W_hh[row * 5 + i];
    }
    const float bias_s = sc * (b_ih[row] + b_hh[row]);

    // h_k is replicated across quad k after the cell update; read lane base+4k
    int a_h[5];
    #pragma unroll
    for (int k = 0; k < 5; ++k) a_h[k] = (base + 4 * k) << 2;

    const float* xb = x + (size_t)b * (TT * 5);

    float hv[5] = {0.f, 0.f, 0.f, 0.f, 0.f};
    float c = 0.f;

    float4 bufA[5], bufB[5];
    #pragma unroll
    for (int i = 0; i < 5; ++i) {
        bufA[i] = *(const float4*)(xb + 0  + 4 * i);   // t = 0..3
        bufB[i] = *(const float4*)(xb + 20 + 4 * i);   // t = 4..7
    }

    auto process4 = [&](const float4* buf) {
        float xs[20];
        *(float4*)&xs[0]  = buf[0];
        *(float4*)&xs[4]  = buf[1];
        *(float4*)&xs[8]  = buf[2];
        *(float4*)&xs[12] = buf[3];
        *(float4*)&xs[16] = buf[4];

        // x-projection for 4 steps (independent chains, good ILP)
        float gx[4];
        #pragma unroll
        for (int s = 0; s < 4; ++s) {
            float a = bias_s;
            #pragma unroll
            for (int i = 0; i < 5; ++i) a = fmaf(wih[i], xs[s * 5 + i], a);
            gx[s] = a;
        }

        #pragma unroll
        for (int s = 0; s < 4; ++s) {
            // own row's recurrent dot + activation (1 per lane)
            float acc = gx[s];
            #pragma unroll
            for (int k = 0; k < 5; ++k) acc = fmaf(whh[k], hv[k], acc);
            const float val = fmaf(selA, rcp_f(1.0f + exp2_f(acc)), selB);

            // unit j's 4 gates live in this quad: 4 DPP broadcasts
            const float iv = qb<0x00>(val);
            const float fv = qb<0x55>(val);
            const float gv = qb<0xAA>(val);
            const float ov = qb<0xFF>(val);

            // ONE cell update per quad (4-way redundant within quad only)
            c = fmaf(fv, c, iv * gv);
            const float ec = exp2_f(c * (2.0f * LOG2E));
            const float tc = fmaf(-2.0f, rcp_f(1.0f + ec), 1.0f);
            const float h  = ov * tc;

            // single LDS round: gather h_0..h_4 from quad-base lanes
            #pragma unroll
            for (int k = 0; k < 5; ++k) hv[k] = bperm(a_h[k], h);
        }
    };

    for (int t0 = 0; t0 < TT; t0 += 8) {
        process4(bufA);                                // steps t0 .. t0+3
        {
            const int tld = (t0 + 8 <= TT - 4) ? (t0 + 8) : (TT - 4);
            const float* p = xb + tld * 5;
            #pragma unroll
            for (int i = 0; i < 5; ++i) bufA[i] = *(const float4*)(p + 4 * i);
        }
        process4(bufB);                                // steps t0+4 .. t0+7
        {
            const int tld = (t0 + 12 <= TT - 4) ? (t0 + 12) : (TT - 4);
            const float* p = xb + tld * 5;
            #pragma unroll
            for (int i = 0; i < 5; ++i) bufB[i] = *(const float4*)(p + 4 * i);
        }
    }

    // hv holds the final hidden state on every lane
    if (write_ok) {
        float p = fc1_b[0];
        float v = fc2_b[0];
        #pragma unroll
        for (int k = 0; k < 5; ++k) {
            p = fmaf(fc1_w[k], hv[k], p);
            v = fmaf(fc2_w[k], hv[k], v);
        }
        out[b] = p;
        out[BTOT + b] = v;
    }
}

extern "C" void kernel_launch(void* const* d_in, const int* in_sizes, int n_in,
                              void* d_out, int out_size, void* d_ws, size_t ws_size,
                              hipStream_t stream) {
    const float* x     = (const float*)d_in[0];
    const float* W_ih  = (const float*)d_in[1];
    const float* W_hh  = (const float*)d_in[2];
    const float* b_ih  = (const float*)d_in[3];
    const float* b_hh  = (const float*)d_in[4];
    const float* fc1_w = (const float*)d_in[5];
    const float* fc1_b = (const float*)d_in[6];
    const float* fc2_w = (const float*)d_in[7];
    const float* fc2_b = (const float*)d_in[8];
    float* out = (float*)d_out;

    const int blocks = (BTOT + 2) / 3;   // 2731 one-wave blocks, 3 batches each -> 2.67 waves/SIMD
    lstm_kernel<<<blocks, 64, 0, stream>>>(x, W_ih, W_hh, b_ih, b_hh,
                                           fc1_w, fc1_b, fc2_w, fc2_b, out);
}